// Round 1
// 213.825 us; speedup vs baseline: 1.0791x; 1.0791x over previous
//
#include <hip/hip_runtime.h>
#include <math.h>

#define NSITES 65536
#define WIN 4096
#define NW 16          // windows per sweep
#define RMAX 64        // tracked rounds per window (observed depth ~7)

// ws layout:
//   recpk  uint2[2*NSITES]   1048576 B  ({site, uniform-bits} per sorted slot, per sweep)
//   ends   int  [NW*RMAX]       4096 B  (cumulative round boundaries, per window)

// wave-aggregated atomic rank: position for value v in counter array c
// (1-based values, v <= vmax; vmax wave-uniform).
__device__ __forceinline__ int agg_pos(int v, int* c, int vmax) {
  int pos = 0;
  const int lane = threadIdx.x & 63;
  for (int vv = 1; vv <= vmax; ++vv) {
    unsigned long long m = __ballot(v == vv);
    if (m) {
      int leader = __ffsll((long long)m) - 1;
      int base = 0;
      if (lane == leader) base = atomicAdd(&c[vv], (int)__popcll(m));
      base = __shfl(base, leader);
      if (v == vv) pos = base + (int)__popcll(m & ((1ull << lane) - 1ull));
    }
  }
  return pos;
}

// ---------------------------------------------------------------------------
// Kernel A: per-window DAG leveling + counting sort + packed record gather.
// One 1024-thread block per window; window-local position grid in LDS.
// (UNCHANGED this round — isolating the executor change; A's counters will
// surface in the next profile as the top dispatch.)
// ---------------------------------------------------------------------------
__global__ __launch_bounds__(1024) void GibbsSched_kernel(
    const int* __restrict__ perm, const float* __restrict__ uni,
    uint2* __restrict__ recpk, int* __restrict__ ends) {
  __shared__ unsigned short posg[NSITES];  // 128 KiB: local pos+1, 0 = absent
  __shared__ unsigned short lvl[WIN];      // 8 KiB
  __shared__ int cnt[RMAX + 1], coff[RMAX + 1];
  __shared__ int chg, bmax;
  const int tid = threadIdx.x;
  const int w = blockIdx.x;
  const int wbase = w * WIN;

  for (int g = tid; g < NSITES / 8; g += 1024)  // 8 ushorts per uint4
    ((uint4*)posg)[g] = make_uint4(0u, 0u, 0u, 0u);
  for (int i = tid; i <= RMAX; i += 1024) { cnt[i] = 0; coff[i] = 0; }
  if (tid == 0) bmax = 0;
  __syncthreads();

  int uvk[4];
#pragma unroll
  for (int k = 0; k < 4; ++k) {
    const int lt = tid + k * 1024;
    uvk[k] = perm[wbase + lt];
    posg[uvk[k]] = (unsigned short)(lt + 1);  // sites unique within a sweep
  }
  __syncthreads();

  unsigned short pred[4][8];
  int myl[4];
#pragma unroll
  for (int k = 0; k < 4; ++k) {
    const int lt = tid + k * 1024;
    const int uv = uvk[k], u = uv >> 8, v = uv & 255;
    const int um = u ? u - 1 : 0, up = u < 255 ? u + 1 : 255;
    const int vm = v ? v - 1 : 0, vp = v < 255 ? v + 1 : 255;
    const int nb8[8] = {(um << 8) | vm, (um << 8) | v, (um << 8) | vp,
                        (u << 8) | vm,                 (u << 8) | vp,
                        (up << 8) | vm, (up << 8) | v, (up << 8) | vp};
#pragma unroll
    for (int j = 0; j < 8; ++j) {
      const int p = posg[nb8[j]];  // clipped dup == self -> p-1==lt, excluded
      pred[k][j] = (p && p - 1 < lt) ? (unsigned short)(p - 1)
                                     : (unsigned short)0xFFFF;
    }
    lvl[lt] = 1;
    myl[k] = 1;
  }
  __syncthreads();

  // monotone Jacobi relaxation to the unique longest-path fixpoint
  for (int pass = 0; pass < 128; ++pass) {
    if (tid == 0) chg = 0;
    __syncthreads();
    bool ch = false;
#pragma unroll
    for (int k = 0; k < 4; ++k) {
      int m = 0;
#pragma unroll
      for (int j = 0; j < 8; ++j) {
        const unsigned short p = pred[k][j];
        if (p != 0xFFFF) m = max(m, (int)lvl[p]);
      }
      const int nl = m + 1;  // levels only grow
      if (nl != myl[k]) {
        myl[k] = nl;
        lvl[tid + k * 1024] = (unsigned short)nl;
        ch = true;
      }
    }
    if (ch) chg = 1;
    __syncthreads();
    if (chg == 0) break;  // full no-change pass == converged
  }

#pragma unroll
  for (int k = 0; k < 4; ++k) atomicMax(&bmax, myl[k]);
  __syncthreads();
  const int vmax = bmax;

#pragma unroll
  for (int k = 0; k < 4; ++k) (void)agg_pos(myl[k], cnt, vmax);  // histogram
  __syncthreads();
  if (tid == 0) {
    int e = 0;
    for (int r = 0; r < RMAX; ++r) {  // cnt[0]==0
      coff[r] = e;
      e += cnt[r];
      ends[w * RMAX + r] = e;  // cumulative end through round r
    }
  }
  __syncthreads();

#pragma unroll
  for (int k = 0; k < 4; ++k) {
    const int pos = agg_pos(myl[k], coff, vmax);
    const int lt = tid + k * 1024;
    const int gp = wbase + pos;
    recpk[gp] = make_uint2((unsigned)uvk[k],
                           __float_as_uint(uni[wbase + lt]));          // sweep 0
    recpk[NSITES + gp] = make_uint2((unsigned)uvk[k],
                                    __float_as_uint(uni[NSITES + wbase + lt]));
  }
}

// ---------------------------------------------------------------------------
// Kernel B: executor — 1 block x 1024 threads.
// Per update: 3 row-window LDS reads (2 dwords each) -> neighbor histogram ->
// one float4 ctab read -> 4 compares -> byte write. No divides, no exp.
// NEW this round: the whole window's 4096 records live in 8 VGPRs/thread
// (4 x uint2, double-buffered across windows) -> zero global reads inside
// rounds; round bounds software-pipelined past the barrier.
// ---------------------------------------------------------------------------
__device__ __forceinline__ void do_update(unsigned char* cell,
                                          const unsigned int* cellw,
                                          const float4* ctab, unsigned uvv,
                                          float r) {
  const int u = uvv >> 8, v = (int)(uvv & 255u);
  const int um = u ? u - 1 : 0, up = u < 255 ? u + 1 : 255;
  const int vm = v ? v - 1 : 0, vp = v < 255 ? v + 1 : 255;
  const int cb = vm >> 2;              // dword col of 8-byte window start
  const int sh0 = (vm & 3) << 3;
  const int shv = (v - vm) << 3;       // 0 or 8
  const int shp = (vp - vm) << 3;      // 8 or 16 (or 8 at right border)
  int acc = 0;  // per-class counts in nibbles (class 4 -> bit16, unused)
  {  // top row: cols vm, v, vp (clipped dups included, matching reference)
    const unsigned int* rw = cellw + (um << 6) + cb;
    const unsigned long long wd =
        ((unsigned long long)rw[1] << 32) | (unsigned long long)rw[0];
    const unsigned wl = (unsigned)(wd >> sh0);
    acc += 1 << ((wl & 255u) << 2);
    acc += 1 << (((wl >> shv) & 255u) << 2);
    acc += 1 << (((wl >> shp) & 255u) << 2);
  }
  {  // middle row: cols vm, vp only (true center excluded exactly once)
    const unsigned int* rw = cellw + (u << 6) + cb;
    const unsigned long long wd =
        ((unsigned long long)rw[1] << 32) | (unsigned long long)rw[0];
    const unsigned wl = (unsigned)(wd >> sh0);
    acc += 1 << ((wl & 255u) << 2);
    acc += 1 << (((wl >> shp) & 255u) << 2);
  }
  {  // bottom row: cols vm, v, vp
    const unsigned int* rw = cellw + (up << 6) + cb;
    const unsigned long long wd =
        ((unsigned long long)rw[1] << 32) | (unsigned long long)rw[0];
    const unsigned wl = (unsigned)(wd >> sh0);
    acc += 1 << ((wl & 255u) << 2);
    acc += 1 << (((wl >> shv) & 255u) << 2);
    acc += 1 << (((wl >> shp) & 255u) << 2);
  }
  const int n0 = acc & 15, n1 = (acc >> 4) & 15, n2 = (acc >> 8) & 15;
  const float4 c = ctab[n0 + 9 * n1 + 81 * n2];
  int cnt = (c.x < r) ? 1 : 0;
  cnt += (c.y < r) ? 1 : 0;
  cnt += (c.z < r) ? 1 : 0;
  cnt += (c.w < r) ? 1 : 0;
  cell[uvv] = (unsigned char)cnt;  // 0..4
}

// Execute all rounds of one window from a register-resident record set.
// R is indexed only by compile-time constants -> stays in VGPRs (rule #20).
__device__ __forceinline__ void run_rounds(unsigned char* cell,
                                           const unsigned int* cellw,
                                           const float4* ctab, const int* le,
                                           const uint2 (&R)[4], int tid) {
  int b = 0, e = le[1];
  for (int rd = 1; rd < RMAX; ++rd) {
    if (b >= WIN) break;  // uniform: window complete
    // pipeline: fetch next round's bounds before the barrier
    const int nb = e;
    const int ne = (rd + 1 < RMAX) ? le[rd + 1] : e;
#pragma unroll
    for (int k = 0; k < 4; ++k) {
      const int s = tid + (k << 10);
      if (s >= b && s < e)
        do_update(cell, cellw, ctab, R[k].x, __uint_as_float(R[k].y));
    }
    __syncthreads();  // round rd writes before round rd+1 reads
    b = nb;
    e = ne;
  }
}

__global__ __launch_bounds__(1024) void GibbsSampler_90443421319469_kernel(
    const int* __restrict__ Xi, const uint2* __restrict__ recpk,
    const float* __restrict__ betap, const int* __restrict__ ends,
    int* __restrict__ out) {
#pragma clang fp contract(off)
  __shared__ __align__(16) unsigned int cellw[NSITES / 4];  // 64 KiB lattice
  __shared__ float4 ctab[732];                              // 11.7 KiB
  __shared__ int lend[NW * RMAX];                           // 4 KiB
  unsigned char* cell = (unsigned char*)cellw;
  const int tid = threadIdx.x;
  const float beta = betap[0];

  // issue window-0 record loads first so HBM latency hides under LDS init
  uint2 ra[4], rb[4];
#pragma unroll
  for (int k = 0; k < 4; ++k) ra[k] = recpk[tid + (k << 10)];

  for (int g = tid; g < NSITES / 4; g += 1024) {
    int4 x = ((const int4*)Xi)[g];
    // pack 4 int32 cells into one dword (byte lanes)
    cellw[g] = (unsigned)(x.x & 255) | ((unsigned)(x.y & 255) << 8) |
               ((unsigned)(x.z & 255) << 16) | ((unsigned)(x.w & 255) << 24);
  }
  lend[tid] = ends[tid];  // NW*RMAX == 1024
  // cumulative softmax table: bit-identical to per-update reference math
  for (int t = tid; t < 729; t += 1024) {
    const int n0 = t % 9, n1 = (t / 9) % 9, n2 = t / 81;
    const int n3 = 8 - n0 - n1 - n2;
    float4 val = make_float4(2.f, 2.f, 2.f, 2.f);  // unreachable combos
    if (n3 >= 0) {
      const int mx = max(max(n0, n1), max(n2, n3));
      const float xm = beta * (float)mx;   // fl(beta*mx), no FMA (contract off)
      const float x0 = beta * (float)n0;
      const float x1 = beta * (float)n1;
      const float x2 = beta * (float)n2;
      const float x3 = beta * (float)n3;
      const float e0 = (float)exp((double)(x0 - xm));
      const float e1 = (float)exp((double)(x1 - xm));
      const float e2 = (float)exp((double)(x2 - xm));
      const float e3 = (float)exp((double)(x3 - xm));
      const float s = ((e0 + e1) + e2) + e3;  // sequential sum, like np/XLA
      const float c0 = e0 / s;                // IEEE f32 divides, like ref
      const float c1 = c0 + e1 / s;
      const float c2 = c1 + e2 / s;
      const float c3 = c2 + e3 / s;
      val = make_float4(c0, c1, c2, c3);
    }
    ctab[t] = val;
  }
  __syncthreads();

  for (int w = 0; w < 2 * NW; ++w) {
    const int ww = w & (NW - 1);
    const int* le = &lend[ww * RMAX];
    const int wn = w + 1;  // prefetch target (guarded; pointer calc only)
    const uint2* rpn = recpk + (wn >> 4) * NSITES + (wn & (NW - 1)) * WIN;
    if ((w & 1) == 0) {
      if (wn < 2 * NW) {
#pragma unroll
        for (int k = 0; k < 4; ++k) rb[k] = rpn[tid + (k << 10)];
      }
      run_rounds(cell, cellw, ctab, le, ra, tid);
    } else {
      if (wn < 2 * NW) {
#pragma unroll
        for (int k = 0; k < 4; ++k) ra[k] = rpn[tid + (k << 10)];
      }
      run_rounds(cell, cellw, ctab, le, rb, tid);
    }
  }

  for (int g = tid; g < NSITES / 4; g += 1024) {
    const unsigned p = cellw[g];
    int4 o;
    o.x = (int)(p & 255u);
    o.y = (int)((p >> 8) & 255u);
    o.z = (int)((p >> 16) & 255u);
    o.w = (int)((p >> 24) & 255u);
    ((int4*)out)[g] = o;
  }
}

extern "C" void kernel_launch(void* const* d_in, const int* in_sizes, int n_in,
                              void* d_out, int out_size, void* d_ws,
                              size_t ws_size, hipStream_t stream) {
  const int* Xi = (const int*)d_in[0];
  const int* perm = (const int*)d_in[1];
  const float* uni = (const float*)d_in[2];
  const float* beta = (const float*)d_in[3];
  int* out = (int*)d_out;

  char* ws = (char*)d_ws;
  uint2* recpk = (uint2*)ws;                 // 1 MiB
  int* ends = (int*)(ws + 2 * NSITES * 8);   // 4 KiB

  GibbsSched_kernel<<<dim3(NW), dim3(1024), 0, stream>>>(perm, uni, recpk,
                                                         ends);
  GibbsSampler_90443421319469_kernel<<<dim3(1), dim3(1024), 0, stream>>>(
      Xi, recpk, beta, ends, out);
}